// Round 7
// baseline (2395.584 us; speedup 1.0000x reference)
//
#include <hip/hip_runtime.h>

// SPINN v7: per-set (32-WG) barriers with arrive/wait split (barrier latency
// hidden under the tree matmul), j-sliced tracking gates (no tg exchange),
// XCD-aware cg clustering (U-weights L2-resident), tree on all 512 threads.
// Coherence: all cross-WG data via agent-scope relaxed atomics (IC); no
// acquire fences ever -> L1/L2 stay warm across all 63 steps.

constexpr int NB  = 128;
constexpr int LL  = 32;
constexpr int TT  = 63;
constexpr int NWG = 256;
constexpr int NTH = 512;
constexpr int SROWS = 64;

struct Params {
  const float* seq; const int* trans;
  const float* Wx[4];              // i,o,f,u ; Wx[2]==W_o (ref bug kept)
  const float* Ul[4]; const float* Ur[4];
  const float* bias[4];            // b_i, b_o, b_f, b_u
  const float* tWih; const float* tWhh; const float* tbih; const float* tbhh;
  const float* th0; const float* tc0;
  float* stack; float* th2g;
  unsigned* bm;
  float* out;
};

__device__ __forceinline__ float sigm(float x) { return 1.0f / (1.0f + __expf(-x)); }
__device__ __forceinline__ float tanh_f(float x) {
  x = fminf(fmaxf(x, -15.0f), 15.0f);
  float e = __expf(2.0f * x);
  return (e - 1.0f) / (e + 1.0f);
}
__device__ __forceinline__ float cohLoad(const float* a) {
  return __hip_atomic_load(const_cast<float*>(a), __ATOMIC_RELAXED, __HIP_MEMORY_SCOPE_AGENT);
}
__device__ __forceinline__ void cohStore(float* a, float v) {
  __hip_atomic_store(a, v, __ATOMIC_RELAXED, __HIP_MEMORY_SCOPE_AGENT);
}
__device__ __forceinline__ void drainvm() {
  asm volatile("s_waitcnt vmcnt(0)" ::: "memory");
}
// callers guarantee: storing threads drained vmcnt, then __syncthreads, then arrive
__device__ __forceinline__ void bar_arrive(unsigned* cnt, unsigned* flag, unsigned gen) {
  if (threadIdx.x == 0) {
    unsigned a = __hip_atomic_fetch_add(cnt, 1u, __ATOMIC_RELAXED,
                                        __HIP_MEMORY_SCOPE_AGENT) + 1u;
    if (a == gen * 32u)
      __hip_atomic_store(flag, gen, __ATOMIC_RELAXED, __HIP_MEMORY_SCOPE_AGENT);
  }
}
__device__ __forceinline__ void bar_wait(unsigned* flag, unsigned gen) {
  if (threadIdx.x == 0) {
    while (__hip_atomic_load(flag, __ATOMIC_RELAXED, __HIP_MEMORY_SCOPE_AGENT) < gen)
      __builtin_amdgcn_s_sleep(1);
  }
  __syncthreads();
}

__launch_bounds__(NTH)
__global__ void spinn_kernel(Params p) {
  const int w = blockIdx.x;
  const int t = threadIdx.x;
  // XCD-aware decode: the 32 WGs on XCD (w&7) share cg-cluster of 4
  const int cg  = (w & 7) * 4 + ((w >> 3) & 3);   // 0..31
  const int bgp = w >> 5;                          // 0..7 (barrier set)
  const int b0  = bgp * 16;
  const int nc0 = cg * 16;
  const int j0  = cg * 2;                          // owned tracking j-slice

  unsigned* cntA = p.bm + (size_t)bgp * 128;
  unsigned* cntB = cntA + 32;
  unsigned* flgA = cntA + 64;
  unsigned* flgB = cntA + 96;

  __shared__ float opAll[16][1540];  // [b][ buf(512) | sp1h(512) | sp2h(512) ]
  __shared__ float th2s[16][68];     // full th2 of our 16 b (prev step)
  __shared__ float accS[8][64][17];  // tree partials [kth][cc][b]
  __shared__ float xS[64][17];
  __shared__ float accT[4][8][17];   // tracking partials [kth][oth][b]
  __shared__ float tcS[16][2];       // tc state, j-slice
  __shared__ float tbg[8];           // tracking bias, j-slice (g*2+jl)
  __shared__ float biasS[4][16];
  __shared__ unsigned char sp1t[TT + 1][16], sp2t[TT + 1][16];
  __shared__ unsigned char buft[TT + 1][16], redt[TT + 1][16];
  __shared__ int anyredt[TT + 1];
  __shared__ unsigned char qstkS[16][40];

  // per-thread tracking weight rows (oth = gate*2 + jl)
  const int oth = t & 7, blT = (t >> 3) & 15, kthT = t >> 7;
  const int trow = (oth >> 1) * 64 + j0 + (oth & 1);
  const float* wihRow = p.tWih + (size_t)trow * 1536;
  const float* whhRow = p.tWhh + (size_t)trow * 64;

  // ---- prologue
  if (t < 8) { int g = t >> 1, jl = t & 1; int j = g * 64 + j0 + jl;
               tbg[t] = p.tbih[j] + p.tbhh[j]; }
  if (t < 64) biasS[t >> 4][t & 15] = p.bias[t >> 4][nc0 + (t & 15)];
  for (int i = t; i < 1024; i += NTH)
    th2s[i >> 6][i & 63] = p.th0[(size_t)(b0 + (i >> 6)) * 64 + (i & 63)];
  if (t < 32) tcS[t >> 1][t & 1] = p.tc0[(size_t)(b0 + (t >> 1)) * 64 + j0 + (t & 1)];
  if (t < 16) {                       // full-schedule sim for our 16 b
    int bl = t, qn = 0, bp = 0;
    for (int s = 1; s <= TT; ++s) {
      int mask = p.trans[(size_t)(b0 + bl) * TT + (s - 1)];
      int s1 = (qn >= 1) ? qstkS[bl][qn - 1] : 0;
      int s2 = (qn >= 2) ? qstkS[bl][qn - 2] : 0;
      int rd = (mask == 1);
      sp1t[s][bl] = (unsigned char)s1;
      sp2t[s][bl] = (unsigned char)s2;
      redt[s][bl] = (unsigned char)rd;
      buft[s][bl] = (unsigned char)((bp < LL) ? bp : LL);
      int qn2 = rd ? (qn - 2) : qn;
      qstkS[bl][qn2] = (unsigned char)s;
      qn = qn2 + 1;
      bp += rd ? 0 : 1;
    }
  }
  __syncthreads();
  if (t == 0) {
    for (int s = 1; s <= TT; ++s) {
      int a = 0;
      for (int bl = 0; bl < 16; ++bl) a |= redt[s][bl];
      anyredt[s] = a;
    }
  }
  // zero our 32-col slice of stack row 0 for our 16 b
  {
    int bl = t >> 5, cc = t & 31;
    int col = (cc < 16) ? (nc0 + cc) : (512 + nc0 + (cc - 16));
    cohStore(p.stack + ((size_t)(b0 + bl) * SROWS) * 1024 + col, 0.0f);
  }
  drainvm();
  __syncthreads();
  unsigned genA = 1, genB = 0;
  bar_arrive(cntA, flgA, genA);
  bar_wait(flgA, genA);

  for (int step = 1; step <= TT; ++step) {
    const int anyred = anyredt[step];

    // ---- stage operands: 16 rows x {buf, sp1_h, sp2_h}; k = t (0..511)
    #pragma unroll 4
    for (int r = 0; r < 16; ++r) {
      int s1 = sp1t[step][r], s2 = sp2t[step][r], bx = buft[step][r];
      float v1 = cohLoad(p.stack + ((size_t)(b0 + r) * SROWS + s1) * 1024 + t);
      float v2 = cohLoad(p.stack + ((size_t)(b0 + r) * SROWS + s2) * 1024 + t);
      float vb = (bx < LL) ? p.seq[((size_t)(b0 + r) * LL + bx) * 1024 + t] : 0.0f;
      opAll[r][512 + t]  = v1;
      opAll[r][1024 + t] = v2;
      opAll[r][t]        = vb;
    }
    // prefetch c_l/c_r/buf for the gate phase (rows are old -> visible)
    float clv = 0.f, crv = 0.f, bhv = 0.f, bcv = 0.f;
    if (t < 256) {
      const int n = t & 15, bl = t >> 4, na = nc0 + n;
      clv = cohLoad(p.stack + ((size_t)(b0 + bl) * SROWS + sp1t[step][bl]) * 1024 + 512 + na);
      crv = cohLoad(p.stack + ((size_t)(b0 + bl) * SROWS + sp2t[step][bl]) * 1024 + 512 + na);
      int bx = buft[step][bl];
      if (bx < LL) {
        bhv = p.seq[((size_t)(b0 + bl) * LL + bx) * 1024 + na];
        bcv = p.seq[((size_t)(b0 + bl) * LL + bx) * 1024 + 512 + na];
      }
    }
    __syncthreads();

    // ---- tracking matmul: all 512 threads, oth(8) x b(16) x kth(4), K=400
    {
      const int k0 = kthT * 400;
      float tacc = 0.f;
      #pragma unroll 2
      for (int kf = 0; kf < 100; ++kf) {
        const int k = k0 + kf * 4;
        const float* ws = (k < 1536) ? (wihRow + k) : (whhRow + (k - 1536));
        const float* os = (k < 1536) ? &opAll[blT][k] : &th2s[blT][k - 1536];
        float4 wv = *(const float4*)ws;
        float4 ov = *(const float4*)os;
        tacc += wv.x*ov.x + wv.y*ov.y + wv.z*ov.z + wv.w*ov.w;
      }
      accT[kthT][oth][blT] = tacc;
    }
    __syncthreads();

    // ---- LSTM j-slice (t<32) -> publish th2 slice EARLY
    if (t < 32) {
      const int jl = t & 1, bl = t >> 1;
      float gi = accT[0][0+jl][bl] + accT[1][0+jl][bl] + accT[2][0+jl][bl] + accT[3][0+jl][bl] + tbg[0+jl];
      float gf = accT[0][2+jl][bl] + accT[1][2+jl][bl] + accT[2][2+jl][bl] + accT[3][2+jl][bl] + tbg[2+jl];
      float gg = accT[0][4+jl][bl] + accT[1][4+jl][bl] + accT[2][4+jl][bl] + accT[3][4+jl][bl] + tbg[4+jl];
      float go = accT[0][6+jl][bl] + accT[1][6+jl][bl] + accT[2][6+jl][bl] + accT[3][6+jl][bl] + tbg[6+jl];
      float c2 = sigm(gf) * tcS[bl][jl] + sigm(gi) * tanh_f(gg);
      float h2 = sigm(go) * tanh_f(c2);
      tcS[bl][jl] = c2;
      cohStore(p.th2g + (size_t)(b0 + bl) * 64 + j0 + jl, h2);
      drainvm();
    }
    __syncthreads();
    bar_arrive(cntB, flgB, ++genB);

    // ---- tree U-matmul (overlaps barrier-B latency): all 512 threads
    if (anyred) {
      const int bth = t & 3, cth = (t >> 2) & 15, kth = t >> 6;
      const int g = cth >> 2;
      const float* Um = (kth < 4) ? p.Ul[g] : p.Ur[g];
      const int koff = (kth & 3) * 128;
      const int nb = nc0 + (cth & 3) * 4;
      const float* w0 = Um + (size_t)(nb + 0) * 512 + koff;
      const float* w1 = Um + (size_t)(nb + 1) * 512 + koff;
      const float* w2 = Um + (size_t)(nb + 2) * 512 + koff;
      const float* w3 = Um + (size_t)(nb + 3) * 512 + koff;
      const int ob = ((kth < 4) ? 512 : 1024) + koff;
      float acc[4][4];
      #pragma unroll
      for (int i = 0; i < 4; ++i)
        #pragma unroll
        for (int j = 0; j < 4; ++j) acc[i][j] = 0.0f;
      #pragma unroll 4
      for (int k4 = 0; k4 < 32; ++k4) {
        const int kk = k4 * 4;
        float4 wv0 = *(const float4*)(w0 + kk);
        float4 wv1 = *(const float4*)(w1 + kk);
        float4 wv2 = *(const float4*)(w2 + kk);
        float4 wv3 = *(const float4*)(w3 + kk);
        #pragma unroll
        for (int bi = 0; bi < 4; ++bi) {
          float4 ov = *(const float4*)&opAll[bth + bi * 4][ob + kk];
          acc[0][bi] += wv0.x*ov.x + wv0.y*ov.y + wv0.z*ov.z + wv0.w*ov.w;
          acc[1][bi] += wv1.x*ov.x + wv1.y*ov.y + wv1.z*ov.z + wv1.w*ov.w;
          acc[2][bi] += wv2.x*ov.x + wv2.y*ov.y + wv2.z*ov.z + wv2.w*ov.w;
          acc[3][bi] += wv3.x*ov.x + wv3.y*ov.y + wv3.z*ov.z + wv3.w*ov.w;
        }
      }
      const int cc0 = cth * 4;
      #pragma unroll
      for (int ci = 0; ci < 4; ++ci)
        #pragma unroll
        for (int bi = 0; bi < 4; ++bi)
          accS[kth][cc0 + ci][bth + bi * 4] = acc[ci][bi];
    }
    bar_wait(flgB, genB);                    // th2 slices of set now visible

    // ---- read full th2 (16b x 64j) -> LDS
    {
      int i0 = t, i1 = t + 512;
      float v0 = cohLoad(p.th2g + (size_t)(b0 + (i0 >> 6)) * 64 + (i0 & 63));
      float v1 = cohLoad(p.th2g + (size_t)(b0 + (i1 >> 6)) * 64 + (i1 & 63));
      th2s[i0 >> 6][i0 & 63] = v0;
      th2s[i1 >> 6][i1 & 63] = v1;
    }
    __syncthreads();

    // ---- x@W (K=64): 64 cc x 16 b, weights L1/L2-hot
    if (anyred) {
      #pragma unroll
      for (int rep = 0; rep < 2; ++rep) {
        const int it = t + rep * 512;
        const int cc = it >> 4, bl = it & 15;
        const float* wr = p.Wx[cc >> 4] + (size_t)(nc0 + (cc & 15)) * 64;
        float x = 0.f;
        #pragma unroll 4
        for (int j4 = 0; j4 < 64; j4 += 4) {
          float4 wv = *(const float4*)(wr + j4);
          float4 xv = *(const float4*)&th2s[bl][j4];
          x += wv.x*xv.x + wv.y*xv.y + wv.z*xv.z + wv.w*xv.w;
        }
        xS[cc][bl] = x;
      }
    }
    __syncthreads();

    // ---- gates + stack row write
    if (t < 256) {
      const int n = t & 15, bl = t >> 4, na = nc0 + n;
      float h, c;
      if (redt[step][bl]) {
        float pre[4];
        #pragma unroll
        for (int g = 0; g < 4; ++g) {
          const int cc = g * 16 + n;
          float s = xS[cc][bl] + biasS[g][n];
          #pragma unroll
          for (int k = 0; k < 8; ++k) s += accS[k][cc][bl];
          pre[g] = s;
        }
        float iv = sigm(pre[0]), ov = sigm(pre[1]);
        float fv = sigm(pre[2]), uv = tanh_f(pre[3]);
        c = iv * uv + fv * (clv + crv);
        h = ov * tanh_f(c);
      } else { h = bhv; c = bcv; }
      float* sr = p.stack + ((size_t)(b0 + bl) * SROWS + step) * 1024;
      cohStore(sr + na, h);
      cohStore(sr + 512 + na, c);
      if (step == TT) p.out[(size_t)(b0 + bl) * 512 + na] = h;
      drainvm();
    }
    __syncthreads();
    bar_arrive(cntA, flgA, ++genA);
    bar_wait(flgA, genA);
  }
}

extern "C" void kernel_launch(void* const* d_in, const int* in_sizes, int n_in,
                              void* d_out, int out_size, void* d_ws, size_t ws_size,
                              hipStream_t stream) {
  Params p;
  p.seq   = (const float*)d_in[0];
  p.trans = (const int*)d_in[1];
  p.Wx[0] = (const float*)d_in[2];   // W_i
  p.Wx[1] = (const float*)d_in[4];   // W_o
  p.Wx[2] = (const float*)d_in[4];   // W_o  (ref bug: f-gate uses W_o)
  p.Wx[3] = (const float*)d_in[5];   // W_u
  p.Ul[0] = (const float*)d_in[6];  p.Ur[0] = (const float*)d_in[7];    // i
  p.Ul[1] = (const float*)d_in[10]; p.Ur[1] = (const float*)d_in[11];   // o
  p.Ul[2] = (const float*)d_in[8];  p.Ur[2] = (const float*)d_in[9];    // f
  p.Ul[3] = (const float*)d_in[12]; p.Ur[3] = (const float*)d_in[13];   // u
  p.bias[0] = (const float*)d_in[14];  // b_i
  p.bias[1] = (const float*)d_in[16];  // b_o
  p.bias[2] = (const float*)d_in[15];  // b_f
  p.bias[3] = (const float*)d_in[17];  // b_u
  p.tWih = (const float*)d_in[18];
  p.tWhh = (const float*)d_in[19];
  p.tbih = (const float*)d_in[20];
  p.tbhh = (const float*)d_in[21];
  p.th0  = (const float*)d_in[22];
  p.tc0  = (const float*)d_in[23];

  float* ws = (float*)d_ws;
  size_t off = 0;
  p.stack = ws + off; off += (size_t)NB * SROWS * 1024;  // 33.5 MB
  p.th2g  = ws + off; off += (size_t)NB * 64;            // 32 KB
  unsigned* barmem = (unsigned*)(ws + off); off += 1024; // 4 KB
  if (off * sizeof(float) > ws_size) return;
  p.bm  = barmem;
  p.out = (float*)d_out;

  hipMemsetAsync(barmem, 0, 1024 * sizeof(unsigned), stream);

  void* args[] = { &p };
  hipError_t e = hipLaunchCooperativeKernel((void*)spinn_kernel, dim3(NWG), dim3(NTH),
                                            args, 0, stream);
  if (e != hipSuccess) {
    (void)hipGetLastError();
    spinn_kernel<<<dim3(NWG), dim3(NTH), 0, stream>>>(p);
  }
}

// Round 8
// 1452.969 us; speedup vs baseline: 1.6488x; 1.6488x over previous
//
#include <hip/hip_runtime.h>

// SPINN v8 = v6 structure (concurrent tree|tracking, LDS-local LSTM, tg
// exchange, fence-free sc1 coherence) + per-set 32-WG barriers (cross-WG
// traffic is b-partitioned; sets independent) + arrive/wait split (seq staging
// and accS pre-reduction run between arrive and wait).

constexpr int NB  = 128;
constexpr int LL  = 32;
constexpr int TT  = 63;
constexpr int NWG = 256;
constexpr int NTH = 512;
constexpr int SROWS = 64;

struct Params {
  const float* seq; const int* trans;
  const float* Wx[4];              // i,o,f,u ; Wx[2]==W_o (ref bug kept)
  const float* Ul[4]; const float* Ur[4];
  const float* bias[4];            // b_i, b_o, b_f, b_u
  const float* tWih; const float* tWhh; const float* tbih; const float* tbhh;
  const float* th0; const float* tc0;
  float* stack; float* tg;
  unsigned* bm;
  float* out;
};

__device__ __forceinline__ float sigm(float x) { return 1.0f / (1.0f + __expf(-x)); }
__device__ __forceinline__ float tanh_f(float x) {
  x = fminf(fmaxf(x, -15.0f), 15.0f);
  float e = __expf(2.0f * x);
  return (e - 1.0f) / (e + 1.0f);
}
__device__ __forceinline__ float cohLoad(const float* a) {
  return __hip_atomic_load(const_cast<float*>(a), __ATOMIC_RELAXED, __HIP_MEMORY_SCOPE_AGENT);
}
__device__ __forceinline__ void cohStore(float* a, float v) {
  __hip_atomic_store(a, v, __ATOMIC_RELAXED, __HIP_MEMORY_SCOPE_AGENT);
}
__device__ __forceinline__ void drainvm() {
  asm volatile("s_waitcnt vmcnt(0)" ::: "memory");
}

// Per-set (32 WG) hierarchical monotonic barrier: 4 sublines x 8 arrivals,
// root x 4, then flag. All relaxed; data visibility via sc1 + drainvm.
// blk layout (words): sub0@0 sub1@32 sub2@64 sub3@96 root@128 flag@160
__device__ __forceinline__ void bar_arrive(unsigned* blk, unsigned gen, int l) {
  if (threadIdx.x == 0) {
    unsigned a = __hip_atomic_fetch_add(blk + (l & 3) * 32, 1u, __ATOMIC_RELAXED,
                                        __HIP_MEMORY_SCOPE_AGENT) + 1u;
    if (a == gen * 8u) {
      unsigned r = __hip_atomic_fetch_add(blk + 128, 1u, __ATOMIC_RELAXED,
                                          __HIP_MEMORY_SCOPE_AGENT) + 1u;
      if (r == gen * 4u)
        __hip_atomic_store(blk + 160, gen, __ATOMIC_RELAXED, __HIP_MEMORY_SCOPE_AGENT);
    }
  }
}
__device__ __forceinline__ void bar_wait(unsigned* blk, unsigned gen) {
  if (threadIdx.x == 0) {
    while (__hip_atomic_load(blk + 160, __ATOMIC_RELAXED, __HIP_MEMORY_SCOPE_AGENT) < gen)
      __builtin_amdgcn_s_sleep(1);
  }
  __syncthreads();
}

__launch_bounds__(NTH)
__global__ void spinn_kernel(Params p) {
  const int w = blockIdx.x;
  const int t = threadIdx.x;
  const int cg  = w & 31;            // col-group (also: XCD = cg%8 shares U)
  const int bgp = w >> 5;            // b-group = barrier set
  const int b0  = bgp * 16;
  const int nc0 = cg * 16;
  const int o0  = cg * 8;            // tracking gate-cols [o0, o0+8)

  unsigned* blkA = p.bm + (size_t)bgp * 512;
  unsigned* blkB = blkA + 256;

  __shared__ float opAll[16][1540];  // [b][ buf(512) | sp1h(512) | sp2h(512) ]
  __shared__ float th2s[16][68];
  __shared__ float tc2s[16][68];
  __shared__ float accS[4][64][17];  // tree partials [kth][cc][b]
  __shared__ float accR[64][17];     // accS reduced over kth
  __shared__ float xS[64][17];
  __shared__ float accT[8][8][17];   // tracking partials [kth][oth][b]
  __shared__ float tbsum[256];
  __shared__ float biasS[4][16];
  __shared__ unsigned char sp1t[TT + 1][16], sp2t[TT + 1][16];
  __shared__ unsigned char buft[TT + 1][16], redt[TT + 1][16];
  __shared__ int anyredt[TT + 1];
  __shared__ unsigned char qstkS[16][40];

  // ---- prologue
  if (t < 256) tbsum[t] = p.tbih[t] + p.tbhh[t];
  if (t < 64) biasS[t >> 4][t & 15] = p.bias[t >> 4][nc0 + (t & 15)];
  for (int i = t; i < 1024; i += NTH) {
    th2s[i >> 6][i & 63] = p.th0[(size_t)(b0 + (i >> 6)) * 64 + (i & 63)];
    tc2s[i >> 6][i & 63] = p.tc0[(size_t)(b0 + (i >> 6)) * 64 + (i & 63)];
  }
  if (t < 16) {                       // full-schedule sim for our 16 b
    int bl = t, qn = 0, bp = 0;
    for (int s = 1; s <= TT; ++s) {
      int mask = p.trans[(size_t)(b0 + bl) * TT + (s - 1)];
      int s1 = (qn >= 1) ? qstkS[bl][qn - 1] : 0;
      int s2 = (qn >= 2) ? qstkS[bl][qn - 2] : 0;
      int rd = (mask == 1);
      sp1t[s][bl] = (unsigned char)s1;
      sp2t[s][bl] = (unsigned char)s2;
      redt[s][bl] = (unsigned char)rd;
      buft[s][bl] = (unsigned char)((bp < LL) ? bp : LL);
      int qn2 = rd ? (qn - 2) : qn;
      qstkS[bl][qn2] = (unsigned char)s;
      qn = qn2 + 1;
      bp += rd ? 0 : 1;
    }
  }
  __syncthreads();
  if (t == 0) {
    for (int s = 1; s <= TT; ++s) {
      int a = 0;
      for (int bl = 0; bl < 16; ++bl) a |= redt[s][bl];
      anyredt[s] = a;
    }
  }
  // zero our 32-col slice of stack row 0 for our 16 b
  {
    int bl = t >> 5, cc = t & 31;
    int col = (cc < 16) ? (nc0 + cc) : (512 + nc0 + (cc - 16));
    cohStore(p.stack + ((size_t)(b0 + bl) * SROWS) * 1024 + col, 0.0f);
  }
  drainvm();
  __syncthreads();
  unsigned genA = 1, genB = 0;
  bar_arrive(blkA, genA, cg);

  for (int step = 1; step <= TT; ++step) {
    const int anyred = anyredt[step];

    // ---- seq-only staging + seq c-prefetch (independent of other WGs)
    #pragma unroll 4
    for (int r = 0; r < 16; ++r) {
      int bx = buft[step][r];
      opAll[r][t] = (bx < LL) ? p.seq[((size_t)(b0 + r) * LL + bx) * 1024 + t] : 0.0f;
    }
    float clv = 0.f, crv = 0.f, bhv = 0.f, bcv = 0.f;
    if (t < 256) {
      const int n = t & 15, bl = t >> 4, na = nc0 + n;
      int bx = buft[step][bl];
      if (bx < LL) {
        bhv = p.seq[((size_t)(b0 + bl) * LL + bx) * 1024 + na];
        bcv = p.seq[((size_t)(b0 + bl) * LL + bx) * 1024 + 512 + na];
      }
    }
    bar_wait(blkA, genA);              // prev-step stack rows now visible

    // ---- stack staging (sc1 from IC)
    #pragma unroll 4
    for (int r = 0; r < 16; ++r) {
      int s1 = sp1t[step][r], s2 = sp2t[step][r];
      float v1 = cohLoad(p.stack + ((size_t)(b0 + r) * SROWS + s1) * 1024 + t);
      float v2 = cohLoad(p.stack + ((size_t)(b0 + r) * SROWS + s2) * 1024 + t);
      opAll[r][512 + t]  = v1;
      opAll[r][1024 + t] = v2;
    }
    if (t < 256) {
      const int n = t & 15, bl = t >> 4, na = nc0 + n;
      clv = cohLoad(p.stack + ((size_t)(b0 + bl) * SROWS + sp1t[step][bl]) * 1024 + 512 + na);
      crv = cohLoad(p.stack + ((size_t)(b0 + bl) * SROWS + sp2t[step][bl]) * 1024 + 512 + na);
    }
    __syncthreads();

    // ---- compute: tree on t<256 (reduce steps) || tracking on t>=256
    if (t < 256) {
      if (anyred) {
        const int bth = t & 3, cth = (t >> 2) & 15, kth = t >> 6;
        const int g = cth >> 2;
        const float* Um = (kth < 2) ? p.Ul[g] : p.Ur[g];
        const int koff = (kth & 1) * 256;
        const int nb = nc0 + (cth & 3) * 4;
        const float* w0 = Um + (size_t)(nb    ) * 512 + koff;
        const float* w1 = Um + (size_t)(nb + 1) * 512 + koff;
        const float* w2 = Um + (size_t)(nb + 2) * 512 + koff;
        const float* w3 = Um + (size_t)(nb + 3) * 512 + koff;
        const int ob = ((kth < 2) ? 512 : 1024) + koff;
        float acc[4][4];
        #pragma unroll
        for (int i = 0; i < 4; ++i)
          #pragma unroll
          for (int j = 0; j < 4; ++j) acc[i][j] = 0.0f;
        #pragma unroll 2
        for (int k4 = 0; k4 < 64; ++k4) {
          const int kk = k4 * 4;
          float4 wv0 = *(const float4*)(w0 + kk);
          float4 wv1 = *(const float4*)(w1 + kk);
          float4 wv2 = *(const float4*)(w2 + kk);
          float4 wv3 = *(const float4*)(w3 + kk);
          #pragma unroll
          for (int bi = 0; bi < 4; ++bi) {
            float4 ov = *(const float4*)&opAll[bi * 4 + bth][ob + kk];
            acc[0][bi] += wv0.x*ov.x + wv0.y*ov.y + wv0.z*ov.z + wv0.w*ov.w;
            acc[1][bi] += wv1.x*ov.x + wv1.y*ov.y + wv1.z*ov.z + wv1.w*ov.w;
            acc[2][bi] += wv2.x*ov.x + wv2.y*ov.y + wv2.z*ov.z + wv2.w*ov.w;
            acc[3][bi] += wv3.x*ov.x + wv3.y*ov.y + wv3.z*ov.z + wv3.w*ov.w;
          }
        }
        const int cc0 = cth * 4;
        #pragma unroll
        for (int ci = 0; ci < 4; ++ci)
          #pragma unroll
          for (int bi = 0; bi < 4; ++bi)
            accS[kth][cc0 + ci][bi * 4 + bth] = acc[ci][bi];
      }
    } else {
      const int tt = t - 256;
      const int oth = tt & 7, bth4 = (tt >> 3) & 3, kth = tt >> 5;  // 8x4x8
      const int oabs = o0 + oth;
      const float* wrow = p.tWih + (size_t)oabs * 1536;
      const float* whh  = p.tWhh + (size_t)oabs * 64;
      const int k0 = kth * 200;
      float tacc[4] = {0.f, 0.f, 0.f, 0.f};
      #pragma unroll 2
      for (int kf = 0; kf < 50; ++kf) {
        const int k = k0 + kf * 4;
        const float* wsrc = (k < 1536) ? (wrow + k) : (whh + (k - 1536));
        float4 wv = *(const float4*)wsrc;
        #pragma unroll
        for (int bi = 0; bi < 4; ++bi) {
          const int r = bi * 4 + bth4;
          const float* os = (k < 1536) ? &opAll[r][k] : &th2s[r][k - 1536];
          float4 ov = *(const float4*)os;
          tacc[bi] += wv.x*ov.x + wv.y*ov.y + wv.z*ov.z + wv.w*ov.w;
        }
      }
      #pragma unroll
      for (int bi = 0; bi < 4; ++bi) accT[kth][oth][bi * 4 + bth4] = tacc[bi];
    }
    __syncthreads();
    if (t < 128) {                        // tg publish: 8 outs x 16 b, sc1
      const int o = t & 7, bl = t >> 3;
      float s = 0.f;
      #pragma unroll
      for (int kt = 0; kt < 8; ++kt) s += accT[kt][o][bl];
      cohStore(p.tg + (size_t)(b0 + bl) * 256 + o0 + o, s);
      drainvm();
    }
    __syncthreads();
    bar_arrive(blkB, ++genB, cg);

    // ---- fill barrier-B latency: reduce accS over kth
    if (anyred) {
      #pragma unroll
      for (int rep = 0; rep < 2; ++rep) {
        const int it = t + rep * 512;
        const int cc = it >> 4, bl = it & 15;
        accR[cc][bl] = accS[0][cc][bl] + accS[1][cc][bl]
                     + accS[2][cc][bl] + accS[3][cc][bl];
      }
    }
    bar_wait(blkB, genB);                 // tg of whole set now visible

    // ---- tracking LSTM elementwise (all 16 b x 64 j, LDS-local state)
    #pragma unroll
    for (int rep = 0; rep < 2; ++rep) {
      const int it = t + rep * 512;
      const int b = it >> 6, j = it & 63;
      const float* tgb = p.tg + (size_t)(b0 + b) * 256;
      float gi = cohLoad(tgb + j)        + tbsum[j];
      float gf = cohLoad(tgb + 64 + j)   + tbsum[64 + j];
      float gg = cohLoad(tgb + 128 + j)  + tbsum[128 + j];
      float go = cohLoad(tgb + 192 + j)  + tbsum[192 + j];
      float c2 = sigm(gf) * tc2s[b][j] + sigm(gi) * tanh_f(gg);
      float h2 = sigm(go) * tanh_f(c2);
      tc2s[b][j] = c2;
      th2s[b][j] = h2;
    }
    __syncthreads();
    if (anyred) {                         // x@W: 64 cc x 16 b, K=64
      #pragma unroll
      for (int rep = 0; rep < 2; ++rep) {
        const int it = t + rep * 512;
        const int cc = it >> 4, bl = it & 15;
        const float* wr = p.Wx[cc >> 4] + (size_t)(nc0 + (cc & 15)) * 64;
        float x = 0.f;
        #pragma unroll 4
        for (int j4 = 0; j4 < 64; j4 += 4) {
          float4 wv = *(const float4*)(wr + j4);
          float4 xv = *(const float4*)&th2s[bl][j4];
          x += wv.x*xv.x + wv.y*xv.y + wv.z*xv.z + wv.w*xv.w;
        }
        xS[cc][bl] = x;
      }
      __syncthreads();
    }
    // ---- gates + stack row write
    if (t < 256) {
      const int n = t & 15, bl = t >> 4, na = nc0 + n;
      float h, c;
      if (redt[step][bl]) {
        float pre[4];
        #pragma unroll
        for (int g = 0; g < 4; ++g) {
          const int cc = g * 16 + n;
          pre[g] = accR[cc][bl] + xS[cc][bl] + biasS[g][n];
        }
        float iv = sigm(pre[0]), ov = sigm(pre[1]);
        float fv = sigm(pre[2]), uv = tanh_f(pre[3]);
        c = iv * uv + fv * (clv + crv);
        h = ov * tanh_f(c);
      } else { h = bhv; c = bcv; }
      float* sr = p.stack + ((size_t)(b0 + bl) * SROWS + step) * 1024;
      cohStore(sr + na, h);
      cohStore(sr + 512 + na, c);
      if (step == TT) p.out[(size_t)(b0 + bl) * 512 + na] = h;
      drainvm();
    }
    __syncthreads();
    bar_arrive(blkA, ++genA, cg);
  }
}

extern "C" void kernel_launch(void* const* d_in, const int* in_sizes, int n_in,
                              void* d_out, int out_size, void* d_ws, size_t ws_size,
                              hipStream_t stream) {
  Params p;
  p.seq   = (const float*)d_in[0];
  p.trans = (const int*)d_in[1];
  p.Wx[0] = (const float*)d_in[2];   // W_i
  p.Wx[1] = (const float*)d_in[4];   // W_o
  p.Wx[2] = (const float*)d_in[4];   // W_o  (ref bug: f-gate uses W_o)
  p.Wx[3] = (const float*)d_in[5];   // W_u
  p.Ul[0] = (const float*)d_in[6];  p.Ur[0] = (const float*)d_in[7];    // i
  p.Ul[1] = (const float*)d_in[10]; p.Ur[1] = (const float*)d_in[11];   // o
  p.Ul[2] = (const float*)d_in[8];  p.Ur[2] = (const float*)d_in[9];    // f
  p.Ul[3] = (const float*)d_in[12]; p.Ur[3] = (const float*)d_in[13];   // u
  p.bias[0] = (const float*)d_in[14];  // b_i
  p.bias[1] = (const float*)d_in[16];  // b_o
  p.bias[2] = (const float*)d_in[15];  // b_f
  p.bias[3] = (const float*)d_in[17];  // b_u
  p.tWih = (const float*)d_in[18];
  p.tWhh = (const float*)d_in[19];
  p.tbih = (const float*)d_in[20];
  p.tbhh = (const float*)d_in[21];
  p.th0  = (const float*)d_in[22];
  p.tc0  = (const float*)d_in[23];

  float* ws = (float*)d_ws;
  size_t off = 0;
  p.stack = ws + off; off += (size_t)NB * SROWS * 1024;  // 33.5 MB
  p.tg    = ws + off; off += (size_t)NB * 256;           // 128 KB
  unsigned* barmem = (unsigned*)(ws + off); off += 4096; // 16 KB
  if (off * sizeof(float) > ws_size) return;
  p.bm  = barmem;
  p.out = (float*)d_out;

  hipMemsetAsync(barmem, 0, 4096 * sizeof(unsigned), stream);

  void* args[] = { &p };
  hipError_t e = hipLaunchCooperativeKernel((void*)spinn_kernel, dim3(NWG), dim3(NTH),
                                            args, 0, stream);
  if (e != hipSuccess) {
    (void)hipGetLastError();
    spinn_kernel<<<dim3(NWG), dim3(NTH), 0, stream>>>(p);
  }
}